// Round 1
// baseline (240.046 us; speedup 1.0000x reference)
//
#include <hip/hip_runtime.h>
#include <math.h>

#define NROWS 524288
#define LATENT 64
#define NUM_CODES 1024
#define BLOCK 256
#define GRID 1024
#define ROWS_PER_BLOCK (NROWS / GRID)            // 512
#define LANES_PER_ROW 8
#define ROWS_PER_ITER 64                         // 2 rows per thread per iter
#define NITER (ROWS_PER_BLOCK / ROWS_PER_ITER)   // 8

typedef float v4f __attribute__((ext_vector_type(4)));

__device__ __forceinline__ v4f ldnt4(const float* p) {
    return __builtin_nontemporal_load((const v4f*)p);
}
__device__ __forceinline__ void stnt4(float* p, v4f v) {
    __builtin_nontemporal_store(v, (v4f*)p);
}

// DPP-fused butterfly add over the 8-lane row group.
// Stage ctrls: 0xB1 = quad_perm [1,0,3,2] (xor 1)
//              0x4E = quad_perm [2,3,0,1] (xor 2)
//              0x141 = row_half_mirror    (xor 7 within aligned 8)
// After xor1+xor2 every lane of an aligned 4-group holds the bit-identical
// 4-group sum, so the mirror step yields sums bit-identical to the old
// ds_swizzle xor4 butterfly.
template <int CTRL>
__device__ __forceinline__ float dpp_add(float x) {
    const int p = __builtin_amdgcn_update_dpp(
        0, __float_as_int(x), CTRL, 0xF, 0xF, true);
    return x + __int_as_float(p);
}

__device__ __forceinline__ float dot8(v4f a, v4f wa, v4f b, v4f wb) {
    float r = a.x * wa.x;
    r = fmaf(a.y, wa.y, r); r = fmaf(a.z, wa.z, r); r = fmaf(a.w, wa.w, r);
    r = fmaf(b.x, wb.x, r); r = fmaf(b.y, wb.y, r);
    r = fmaf(b.z, wb.z, r); r = fmaf(b.w, wb.w, r);
    return r;
}

// Quantize one level-8 component (rintf = round half-to-even, matches jnp.round).
__device__ __forceinline__ float q7(float s, int& bin) {
    float t  = tanhf(s);
    float zs = (t + 1.0f) * 0.5f * 7.0f;
    float r  = rintf(zs);
    r = fminf(fmaxf(r, 0.0f), 7.0f);
    bin = (int)r;
    return r - 3.5f;
}

struct RowRes { v4f oA, oB; int idx; };

__device__ __forceinline__ RowRes process_row(
    v4f vA, v4f vB,
    const v4f winA[4], const v4f winB[4],
    const v4f woA[4], const v4f woB[4])
{
    float s0 = dot8(vA, winA[0], vB, winB[0]);
    float s1 = dot8(vA, winA[1], vB, winB[1]);
    float s2 = dot8(vA, winA[2], vB, winB[2]);
    float s3 = dot8(vA, winA[3], vB, winB[3]);

    // 8-lane butterfly sum, all in VALU DPP (no LDS pipe, no lgkmcnt chain).
    s0 = dpp_add<0xB1>(s0);  s1 = dpp_add<0xB1>(s1);
    s2 = dpp_add<0xB1>(s2);  s3 = dpp_add<0xB1>(s3);
    s0 = dpp_add<0x4E>(s0);  s1 = dpp_add<0x4E>(s1);
    s2 = dpp_add<0x4E>(s2);  s3 = dpp_add<0x4E>(s3);
    s0 = dpp_add<0x141>(s0); s1 = dpp_add<0x141>(s1);
    s2 = dpp_add<0x141>(s2); s3 = dpp_add<0x141>(s3);

    int b0, b1, b2;
    const float c0 = q7(s0, b0);
    const float c1 = q7(s1, b1);
    const float c2 = q7(s2, b2);
    // level-2 component: boundary at s3==0; rint(0.5)==0 so strict > is correct
    const int   b3 = (s3 > 0.0f) ? 1 : 0;
    const float c3 = (float)b3 - 0.5f;

    RowRes r;
    r.oA.x = fmaf(c0, woA[0].x, fmaf(c1, woA[0].y, fmaf(c2, woA[0].z, c3 * woA[0].w)));
    r.oA.y = fmaf(c0, woA[1].x, fmaf(c1, woA[1].y, fmaf(c2, woA[1].z, c3 * woA[1].w)));
    r.oA.z = fmaf(c0, woA[2].x, fmaf(c1, woA[2].y, fmaf(c2, woA[2].z, c3 * woA[2].w)));
    r.oA.w = fmaf(c0, woA[3].x, fmaf(c1, woA[3].y, fmaf(c2, woA[3].z, c3 * woA[3].w)));
    r.oB.x = fmaf(c0, woB[0].x, fmaf(c1, woB[0].y, fmaf(c2, woB[0].z, c3 * woB[0].w)));
    r.oB.y = fmaf(c0, woB[1].x, fmaf(c1, woB[1].y, fmaf(c2, woB[1].z, c3 * woB[1].w)));
    r.oB.z = fmaf(c0, woB[2].x, fmaf(c1, woB[2].y, fmaf(c2, woB[2].z, c3 * woB[2].w)));
    r.oB.w = fmaf(c0, woB[3].x, fmaf(c1, woB[3].y, fmaf(c2, woB[3].z, c3 * woB[3].w)));
    r.idx = b0 + (b1 << 3) + (b2 << 6) + (b3 << 9);
    return r;
}

__global__ __launch_bounds__(BLOCK, 4) void fsq_main(
    const float* __restrict__ z_e,    // (B, 64)
    const float* __restrict__ W_in,   // (4, 64) row-major
    const float* __restrict__ W_out,  // (64, 4) row-major
    float* __restrict__ z_q,          // (B, 64)
    float* __restrict__ idx_out,      // (B) stored as float
    unsigned int* __restrict__ counts)// (1024) pre-zeroed; global atomic flush
{
    __shared__ unsigned int lhist[NUM_CODES];
    const int tid = threadIdx.x;
    for (int i = tid; i < NUM_CODES; i += BLOCK) lhist[i] = 0;

    const int sub = tid & (LANES_PER_ROW - 1);  // lane within 8-lane row group
    const int rid = tid >> 3;                   // row slot (0..31)
    const int l0  = sub * 4;                    // fragment A col; B is +32

    v4f winA[4], winB[4], woA[4], woB[4];
    #pragma unroll
    for (int f = 0; f < 4; ++f) {
        winA[f] = *(const v4f*)(W_in + f * LATENT + l0);
        winB[f] = *(const v4f*)(W_in + f * LATENT + 32 + l0);
    }
    #pragma unroll
    for (int j = 0; j < 4; ++j) {
        woA[j] = *(const v4f*)(W_out + (l0 + j) * 4);
        woB[j] = *(const v4f*)(W_out + (32 + l0 + j) * 4);
    }

    __syncthreads();

    // Thread handles rows (base+rid) and (base+rid+32) each iteration.
    const size_t rowA0 = (size_t)blockIdx.x * ROWS_PER_BLOCK + rid;
    const float* pA = z_e + rowA0 * LATENT + l0;
    const float* pB = pA + 32 * LATENT;

    v4f aA = ldnt4(pA), aB = ldnt4(pA + 32);   // row A fragments
    v4f bA = ldnt4(pB), bB = ldnt4(pB + 32);   // row B fragments

    for (int it = 0; it < NITER; ++it) {
        v4f naA, naB, nbA, nbB;
        const bool more = (it + 1 < NITER);
        if (more) {
            const float* qA = pA + (size_t)(it + 1) * ROWS_PER_ITER * LATENT;
            const float* qB = qA + 32 * LATENT;
            naA = ldnt4(qA); naB = ldnt4(qA + 32);
            nbA = ldnt4(qB); nbB = ldnt4(qB + 32);
        }

        const RowRes rA = process_row(aA, aB, winA, winB, woA, woB);
        const RowRes rB = process_row(bA, bB, winA, winB, woA, woB);

        const size_t rowA = rowA0 + (size_t)it * ROWS_PER_ITER;
        const size_t rowB = rowA + 32;
        float* qa = z_q + rowA * LATENT + l0;
        float* qb = z_q + rowB * LATENT + l0;
        stnt4(qa, rA.oA);       stnt4(qa + 32, rA.oB);
        stnt4(qb, rB.oA);       stnt4(qb + 32, rB.oB);

        if (sub == 0) {
            atomicAdd(&lhist[rA.idx], 1u);
            atomicAdd(&lhist[rB.idx], 1u);
            idx_out[rowA] = (float)rA.idx;
            idx_out[rowB] = (float)rB.idx;
        }

        if (more) { aA = naA; aB = naB; bA = nbA; bB = nbB; }
    }

    __syncthreads();

    // Device-scope flush, staggered start per block to spread atomic
    // contention across the 1024 counter addresses.
    const int start = (blockIdx.x * 251) & (NUM_CODES - 1);
    for (int k = 0; k < NUM_CODES; k += BLOCK) {
        const int i = (start + tid + k) & (NUM_CODES - 1);
        const unsigned int c = lhist[i];
        if (c) atomicAdd(&counts[i], c);
    }
}

__global__ __launch_bounds__(1024) void fsq_stats(
    const unsigned int* __restrict__ counts,
    float* __restrict__ out_scalars)   // 4 floats
{
    const int tid = threadIdx.x;   // one per code
    const unsigned int c = counts[tid];

    const float p = (float)c / (float)NROWS;
    double t = (double)(p * logf(p + 1e-10f));
    int nz = (c != 0) ? 1 : 0;

    #pragma unroll
    for (int off = 32; off > 0; off >>= 1) {
        t  += __shfl_down(t, off);
        nz += __shfl_down(nz, off);
    }
    __shared__ double sh_t[16];
    __shared__ int    sh_nz[16];
    const int wid = tid >> 6;
    if ((tid & 63) == 0) { sh_t[wid] = t; sh_nz[wid] = nz; }
    __syncthreads();
    if (tid == 0) {
        double T = 0.0; int N = 0;
        #pragma unroll
        for (int i = 0; i < 16; ++i) { T += sh_t[i]; N += sh_nz[i]; }
        out_scalars[0] = 0.0f;                        // commitment_loss
        out_scalars[1] = 0.0f;                        // codebook_loss
        out_scalars[2] = expf((float)(-T));           // perplexity
        out_scalars[3] = (float)N / (float)NUM_CODES; // utilization
    }
}

extern "C" void kernel_launch(void* const* d_in, const int* in_sizes, int n_in,
                              void* d_out, int out_size, void* d_ws, size_t ws_size,
                              hipStream_t stream) {
    const float* z_e   = (const float*)d_in[0];
    const float* W_in  = (const float*)d_in[1];
    const float* W_out = (const float*)d_in[2];

    float* out     = (float*)d_out;
    float* zq      = out;                          // B*64
    float* idxs    = out + (size_t)NROWS * LATENT; // B
    float* scalars = idxs + NROWS;                 // 4

    unsigned int* counts = (unsigned int*)d_ws;    // 1024 (ws is poisoned 0xAA each call)

    hipMemsetAsync(counts, 0, NUM_CODES * sizeof(unsigned int), stream);
    fsq_main<<<GRID, BLOCK, 0, stream>>>(z_e, W_in, W_out, zq, idxs, counts);
    fsq_stats<<<1, 1024, 0, stream>>>(counts, scalars);
}